// Round 14
// baseline (91.529 us; speedup 1.0000x reference)
//
#include <hip/hip_runtime.h>
#include <cstdint>
#include <cstddef>

#define RANK 16

// ---------------------------------------------------------------------------
// Kernel 1: mix LoRA factors with per-(batch,split) skill weights. [r5 proven]
//   At[b][r][k] = sum_s w[b][q][s] * la[q][s][d][r],   k = q*512 + d  (k-major)
//   Bm[b][r][o] = 2 * sum_s w[b][q][s] * lb[q][s][r][dd], o = q*512 + dd
// ---------------------------------------------------------------------------
__global__ __launch_bounds__(256) void skilled_lora_mix(
    const float* __restrict__ w,   // [8][4][8]
    const float* __restrict__ la,  // [4][8][512][16]
    const float* __restrict__ lb,  // [4][8][16][512]
    float* __restrict__ At,        // [8][16][2048]
    float* __restrict__ Bm)        // [8][16][2048], pre-scaled by 2
{
  const int j = blockIdx.x * 256 + threadIdx.x;
  if (j < 65536) {
    const int k = (j & 511) * 4;
    const int r = (j >> 9) & 15;
    const int b = j >> 13;
    const int q = k >> 9;
    const int d = k & 511;
    const float* wb = w + (b * 4 + q) * 8;
    float4 acc = make_float4(0.f, 0.f, 0.f, 0.f);
#pragma unroll
    for (int s = 0; s < 8; ++s) {
      const float ws = wb[s];
      const float* lap = la + (size_t)(((q * 8 + s) * 512 + d) * 16 + r);
      acc.x = fmaf(ws, lap[0],  acc.x);
      acc.y = fmaf(ws, lap[16], acc.y);
      acc.z = fmaf(ws, lap[32], acc.z);
      acc.w = fmaf(ws, lap[48], acc.w);
    }
    *reinterpret_cast<float4*>(At + (size_t)((b * 16 + r) * 2048 + k)) = acc;
  } else {
    const int jj = j - 65536;
    const int o  = (jj & 511) * 4;
    const int r  = (jj >> 9) & 15;
    const int b  = jj >> 13;
    const int q  = o >> 9;
    const int dd = o & 511;
    const float* wb = w + (b * 4 + q) * 8;
    float4 acc = make_float4(0.f, 0.f, 0.f, 0.f);
#pragma unroll
    for (int s = 0; s < 8; ++s) {
      const float ws = wb[s];
      const float4 v = *reinterpret_cast<const float4*>(
          lb + (size_t)(((q * 8 + s) * 16 + r) * 512 + dd));
      acc.x = fmaf(ws, v.x, acc.x);
      acc.y = fmaf(ws, v.y, acc.y);
      acc.z = fmaf(ws, v.z, acc.z);
      acc.w = fmaf(ws, v.w, acc.w);
    }
    acc.x *= 2.f; acc.y *= 2.f; acc.z *= 2.f; acc.w *= 2.f;
    *reinterpret_cast<float4*>(Bm + (size_t)((b * 16 + r) * 2048 + o)) = acc;
  }
}

// ---------------------------------------------------------------------------
// Kernel 2 (phase A): tmp[b][row][r] = sum_k X[b][row][k] * A[b][k][r]
//
// ROUND-14: REVERT to the measured-best structure (r4/r5, ~37us) — the
// session's four MFMA rewrites all measured 47-50us; the fp32 wave-private
// LDS version remains the best phase A ever observed. One conservative
// upgrade: X staged with float4 (8x ds/global b128 per chunk instead of
// 32x b32); layout and compute loop byte-identical to r4.
// Block: 256 thr = 4 waves, 32 rows; wave owns k-window [wv*512, +512).
// Per 64-k chunk: stage X (32x64, stride-65) + At tile (64x16) into
// wave-private LDS; compute 32 kk x (1 ds_read_b32 + 4 broadcast
// ds_read_b128 + 16 FMA). No barriers in the hot loop. (256,2), 66KB LDS
// -> 2 blocks/CU.
// ---------------------------------------------------------------------------
#define ROWS_A 32
#define KWIN   512
#define KCH    64

__global__ __launch_bounds__(256, 2) void lora_phase_a(
    const float* __restrict__ X,    // [8][2048][2048]
    const float* __restrict__ At,   // [8][16][2048] (k-major per r)
    float* __restrict__ tmp)        // [8][2048][16]
{
  __shared__ float bufX[4][ROWS_A][65];                 // 33.3 KB
  __shared__ __align__(16) float bufA[4][KCH][RANK];    // 16 KB
  __shared__ __align__(16) float part[8][ROWS_A][RANK]; // 16 KB

  const int tid   = threadIdx.x;
  const int lane  = tid & 63;
  const int wv    = tid >> 6;            // 0..3
  const int b     = blockIdx.x >> 6;     // 8 batches x 64 row-tiles
  const int rt    = blockIdx.x & 63;
  const int row0  = rt * ROWS_A;
  const int kw    = wv * KWIN;

  const int row32 = lane & 31;
  const int h     = lane >> 5;           // k-half within chunk
  const int rA    = lane & 15;           // for At staging
  const int k16   = lane >> 4;

  const int sr    = lane >> 4;           // X staging: 4 rows / instr
  const int sc    = (lane & 15) * 4;     // 16 lanes x float4 = 64 floats/row

  const float* Xb = X + ((size_t)(b * 2048 + row0)) * 2048;
  const float* Ab = At + (size_t)b * (RANK * 2048);

  float acc[RANK];
#pragma unroll
  for (int r = 0; r < RANK; ++r) acc[r] = 0.f;

  for (int c = 0; c < KWIN / KCH; ++c) {   // 8 chunks
    const int kbase = kw + c * KCH;

    // ---- stage X: 32 rows x 64 floats as 8 b128 loads (1KB/instr) ----
#pragma unroll
    for (int i = 0; i < 8; ++i) {
      const int row = i * 4 + sr;
      const float4 v = *reinterpret_cast<const float4*>(
          Xb + (size_t)row * 2048 + kbase + sc);
      float* d = &bufX[wv][row][sc];
      d[0] = v.x; d[1] = v.y; d[2] = v.z; d[3] = v.w;
    }

    // ---- stage At tile: 64k x 16r, from k-major At[b][r][k] ----
#pragma unroll
    for (int i = 0; i < 4; ++i) {
      const float4 v = *reinterpret_cast<const float4*>(
          Ab + (size_t)rA * 2048 + kbase + i * 16 + k16 * 4);
      bufA[wv][i * 16 + k16 * 4 + 0][rA] = v.x;
      bufA[wv][i * 16 + k16 * 4 + 1][rA] = v.y;
      bufA[wv][i * 16 + k16 * 4 + 2][rA] = v.z;
      bufA[wv][i * 16 + k16 * 4 + 3][rA] = v.w;
    }
    // wave-private buffers: same-wave DS ordering; no barrier needed.

    // ---- compute: 32 kk (this lane's k-half) x 16 r ----
    const float* xr = &bufX[wv][row32][h * 32];
    const float* ar = &bufA[wv][h * 32][0];
#pragma unroll 4
    for (int kk = 0; kk < 32; ++kk) {
      const float x = xr[kk];
      const float4 a0 = *reinterpret_cast<const float4*>(ar + kk * RANK);
      const float4 a1 = *reinterpret_cast<const float4*>(ar + kk * RANK + 4);
      const float4 a2 = *reinterpret_cast<const float4*>(ar + kk * RANK + 8);
      const float4 a3 = *reinterpret_cast<const float4*>(ar + kk * RANK + 12);
      acc[0]  = fmaf(x, a0.x, acc[0]);  acc[1]  = fmaf(x, a0.y, acc[1]);
      acc[2]  = fmaf(x, a0.z, acc[2]);  acc[3]  = fmaf(x, a0.w, acc[3]);
      acc[4]  = fmaf(x, a1.x, acc[4]);  acc[5]  = fmaf(x, a1.y, acc[5]);
      acc[6]  = fmaf(x, a1.z, acc[6]);  acc[7]  = fmaf(x, a1.w, acc[7]);
      acc[8]  = fmaf(x, a2.x, acc[8]);  acc[9]  = fmaf(x, a2.y, acc[9]);
      acc[10] = fmaf(x, a2.z, acc[10]); acc[11] = fmaf(x, a2.w, acc[11]);
      acc[12] = fmaf(x, a3.x, acc[12]); acc[13] = fmaf(x, a3.y, acc[13]);
      acc[14] = fmaf(x, a3.z, acc[14]); acc[15] = fmaf(x, a3.w, acc[15]);
    }
  }

  // ---- park per-(wave,half) partials, then 8-way reduce ----
  float* pp = &part[wv * 2 + h][row32][0];
#pragma unroll
  for (int rq = 0; rq < 4; ++rq)
    *reinterpret_cast<float4*>(pp + rq * 4) =
        make_float4(acc[rq * 4], acc[rq * 4 + 1], acc[rq * 4 + 2], acc[rq * 4 + 3]);
  __syncthreads();

#pragma unroll
  for (int v = tid; v < ROWS_A * RANK; v += 256) {
    const int row = v >> 4;        // 0..31
    const int r   = v & 15;
    float s = 0.f;
#pragma unroll
    for (int p = 0; p < 8; ++p) s += part[p][row][r];
    tmp[((size_t)(b * 2048 + row0 + row)) * RANK + r] = s;
  }
}

// ---------------------------------------------------------------------------
// Kernel 3 (phase B): out[b][row][o] = sum_r tmp[b][row][r] * Bm[b][r][o]
// ROUND-14: revert to the r6 measured config (~29us): grid 1024, 32 rows,
// (256,2), B-slab in 64 VGPR, block-uniform scalar tmp loads.
// ---------------------------------------------------------------------------
__global__ __launch_bounds__(256, 2) void lora_phase_b(
    const float* __restrict__ tmp,  // [8][2048][16]
    const float* __restrict__ Bm,   // [8][16][2048] (pre-scaled by 2)
    float* __restrict__ out)        // [8][2048][2048]
{
  const int tid  = threadIdx.x;
  const int b    = blockIdx.x >> 7;          // 8 batches x 128 blocks
  const int oh   = (blockIdx.x >> 6) & 1;    // column half
  const int rt   = blockIdx.x & 63;          // row tile
  const int row0 = rt * 32;
  const int o0   = oh * 1024 + tid * 4;

  const float* Bb = Bm + (size_t)b * (RANK * 2048) + o0;
  float4 B4[RANK];
#pragma unroll
  for (int r = 0; r < RANK; ++r)
    B4[r] = *reinterpret_cast<const float4*>(Bb + (size_t)r * 2048);

  const float* tp = tmp + ((size_t)(b * 2048 + row0)) * RANK;
  float* op = out + ((size_t)(b * 2048 + row0)) * 2048 + o0;

#pragma unroll 4
  for (int rr = 0; rr < 32; ++rr) {
    const float4 t0 = *reinterpret_cast<const float4*>(tp + rr * RANK);
    const float4 t1 = *reinterpret_cast<const float4*>(tp + rr * RANK + 4);
    const float4 t2 = *reinterpret_cast<const float4*>(tp + rr * RANK + 8);
    const float4 t3 = *reinterpret_cast<const float4*>(tp + rr * RANK + 12);
    float4 a = make_float4(0.f, 0.f, 0.f, 0.f);
    a.x = fmaf(t0.x, B4[0].x, a.x);  a.y = fmaf(t0.x, B4[0].y, a.y);
    a.z = fmaf(t0.x, B4[0].z, a.z);  a.w = fmaf(t0.x, B4[0].w, a.w);
    a.x = fmaf(t0.y, B4[1].x, a.x);  a.y = fmaf(t0.y, B4[1].y, a.y);
    a.z = fmaf(t0.y, B4[1].z, a.z);  a.w = fmaf(t0.y, B4[1].w, a.w);
    a.x = fmaf(t0.z, B4[2].x, a.x);  a.y = fmaf(t0.z, B4[2].y, a.y);
    a.z = fmaf(t0.z, B4[2].z, a.z);  a.w = fmaf(t0.z, B4[2].w, a.w);
    a.x = fmaf(t0.w, B4[3].x, a.x);  a.y = fmaf(t0.w, B4[3].y, a.y);
    a.z = fmaf(t0.w, B4[3].z, a.z);  a.w = fmaf(t0.w, B4[3].w, a.w);
    a.x = fmaf(t1.x, B4[4].x, a.x);  a.y = fmaf(t1.x, B4[4].y, a.y);
    a.z = fmaf(t1.x, B4[4].z, a.z);  a.w = fmaf(t1.x, B4[4].w, a.w);
    a.x = fmaf(t1.y, B4[5].x, a.x);  a.y = fmaf(t1.y, B4[5].y, a.y);
    a.z = fmaf(t1.y, B4[5].z, a.z);  a.w = fmaf(t1.y, B4[5].w, a.w);
    a.x = fmaf(t1.z, B4[6].x, a.x);  a.y = fmaf(t1.z, B4[6].y, a.y);
    a.z = fmaf(t1.z, B4[6].z, a.z);  a.w = fmaf(t1.z, B4[6].w, a.w);
    a.x = fmaf(t1.w, B4[7].x, a.x);  a.y = fmaf(t1.w, B4[7].y, a.y);
    a.z = fmaf(t1.w, B4[7].z, a.z);  a.w = fmaf(t1.w, B4[7].w, a.w);
    a.x = fmaf(t2.x, B4[8].x, a.x);  a.y = fmaf(t2.x, B4[8].y, a.y);
    a.z = fmaf(t2.x, B4[8].z, a.z);  a.w = fmaf(t2.x, B4[8].w, a.w);
    a.x = fmaf(t2.y, B4[9].x, a.x);  a.y = fmaf(t2.y, B4[9].y, a.y);
    a.z = fmaf(t2.y, B4[9].z, a.z);  a.w = fmaf(t2.y, B4[9].w, a.w);
    a.x = fmaf(t2.z, B4[10].x, a.x); a.y = fmaf(t2.z, B4[10].y, a.y);
    a.z = fmaf(t2.z, B4[10].z, a.z); a.w = fmaf(t2.z, B4[10].w, a.w);
    a.x = fmaf(t2.w, B4[11].x, a.x); a.y = fmaf(t2.w, B4[11].y, a.y);
    a.z = fmaf(t2.w, B4[11].z, a.z); a.w = fmaf(t2.w, B4[11].w, a.w);
    a.x = fmaf(t3.x, B4[12].x, a.x); a.y = fmaf(t3.x, B4[12].y, a.y);
    a.z = fmaf(t3.x, B4[12].z, a.z); a.w = fmaf(t3.x, B4[12].w, a.w);
    a.x = fmaf(t3.y, B4[13].x, a.x); a.y = fmaf(t3.y, B4[13].y, a.y);
    a.z = fmaf(t3.y, B4[13].z, a.z); a.w = fmaf(t3.y, B4[13].w, a.w);
    a.x = fmaf(t3.z, B4[14].x, a.x); a.y = fmaf(t3.z, B4[14].y, a.y);
    a.z = fmaf(t3.z, B4[14].z, a.z); a.w = fmaf(t3.z, B4[14].w, a.w);
    a.x = fmaf(t3.w, B4[15].x, a.x); a.y = fmaf(t3.w, B4[15].y, a.y);
    a.z = fmaf(t3.w, B4[15].z, a.z); a.w = fmaf(t3.w, B4[15].w, a.w);
    *reinterpret_cast<float4*>(op + (size_t)rr * 2048) = a;
  }
}

// ---------------------------------------------------------------------------
extern "C" void kernel_launch(void* const* d_in, const int* in_sizes, int n_in,
                              void* d_out, int out_size, void* d_ws, size_t ws_size,
                              hipStream_t stream) {
  const float* input = (const float*)d_in[0];   // [8][2048][2048]
  const float* w     = (const float*)d_in[1];   // [8][4][8]
  const float* la    = (const float*)d_in[2];   // [4][8][512][16]
  const float* lb    = (const float*)d_in[3];   // [4][8][16][512]
  float* outp = (float*)d_out;

  float* At  = (float*)d_ws;                    // 262144 floats (1 MB)
  float* Bm  = At + 8 * RANK * 2048;            // 262144 floats (1 MB)
  float* tmp = Bm + 8 * RANK * 2048;            // 262144 floats (1 MB)

  skilled_lora_mix<<<512, 256, 0, stream>>>(w, la, lb, At, Bm);
  lora_phase_a<<<512, 256, 0, stream>>>(input, At, tmp);
  lora_phase_b<<<1024, 256, 0, stream>>>(tmp, Bm, outp);
}

// Round 15
// 80.636 us; speedup vs baseline: 1.1351x; 1.1351x over previous
//
#include <hip/hip_runtime.h>
#include <hip/hip_bf16.h>
#include <cstdint>
#include <cstddef>

#define RANK 16

typedef __attribute__((ext_vector_type(8))) short bf16x8;   // 8 bf16 (4 VGPRs)
typedef __attribute__((ext_vector_type(4))) float f32x4;    // MFMA C/D

static __device__ __forceinline__ short f2bf(float f) {
  __hip_bfloat16 h = __float2bfloat16(f);
  return *reinterpret_cast<short*>(&h);
}

// ---------------------------------------------------------------------------
// Kernel 1: mix LoRA factors with per-(batch,split) skill weights. [r8 proven]
//   Amt[b][r][k] = bf16( sum_s w[b][q][s] * la[q][s][d][r] ), k = q*512 + d
//   Bm[b][r][o]  = 2 * sum_s w[b][q][s] * lb[q][s][r][dd],   o = q*512 + dd
// ---------------------------------------------------------------------------
__global__ __launch_bounds__(256) void skilled_lora_mix(
    const float* __restrict__ w,       // [8][4][8]
    const float* __restrict__ la,      // [4][8][512][16]
    const float* __restrict__ lb,      // [4][8][16][512]
    __hip_bfloat16* __restrict__ Amt,  // [8][16][2048] bf16
    float* __restrict__ Bm)            // [8][16][2048] fp32, pre-scaled by 2
{
  const int j = blockIdx.x * 256 + threadIdx.x;
  if (j < 65536) {
    const int r0 = (j & 3) * 4;
    const int k  = (j >> 2) & 2047;
    const int b  = j >> 13;
    const int q  = k >> 9;
    const int d  = k & 511;
    const float* wb = w + (b * 4 + q) * 8;
    float4 acc = make_float4(0.f, 0.f, 0.f, 0.f);
#pragma unroll
    for (int s = 0; s < 8; ++s) {
      const float ws = wb[s];
      const float4 v = *reinterpret_cast<const float4*>(
          la + (size_t)(((q * 8 + s) * 512 + d) * 16 + r0));
      acc.x = fmaf(ws, v.x, acc.x);
      acc.y = fmaf(ws, v.y, acc.y);
      acc.z = fmaf(ws, v.z, acc.z);
      acc.w = fmaf(ws, v.w, acc.w);
    }
    Amt[((size_t)(b * 16 + r0 + 0)) * 2048 + k] = __float2bfloat16(acc.x);
    Amt[((size_t)(b * 16 + r0 + 1)) * 2048 + k] = __float2bfloat16(acc.y);
    Amt[((size_t)(b * 16 + r0 + 2)) * 2048 + k] = __float2bfloat16(acc.z);
    Amt[((size_t)(b * 16 + r0 + 3)) * 2048 + k] = __float2bfloat16(acc.w);
  } else {
    const int jj = j - 65536;
    const int o  = (jj & 511) * 4;
    const int r  = (jj >> 9) & 15;
    const int b  = jj >> 13;
    const int q  = o >> 9;
    const int dd = o & 511;
    const float* wb = w + (b * 4 + q) * 8;
    float4 acc = make_float4(0.f, 0.f, 0.f, 0.f);
#pragma unroll
    for (int s = 0; s < 8; ++s) {
      const float ws = wb[s];
      const float4 v = *reinterpret_cast<const float4*>(
          lb + (size_t)(((q * 8 + s) * 16 + r) * 512 + dd));
      acc.x = fmaf(ws, v.x, acc.x);
      acc.y = fmaf(ws, v.y, acc.y);
      acc.z = fmaf(ws, v.z, acc.z);
      acc.w = fmaf(ws, v.w, acc.w);
    }
    acc.x *= 2.f; acc.y *= 2.f; acc.z *= 2.f; acc.w *= 2.f;
    *reinterpret_cast<float4*>(Bm + (size_t)((b * 16 + r) * 2048 + o)) = acc;
  }
}

// ---------------------------------------------------------------------------
// Kernel 2 (fused, fine-grained): out[b][rows16][:] = (X@A)@B per 16-row tile
//
// ROUND-15: overlap experiment with the r10 confound removed. A-phase reads
// (2.9 TB/s wall, cause unknown) and B-phase writes use different memory
// directions; a 3-launch serial structure leaves each idle half the time.
// r10's fused test was polluted by 2-big-blocks/CU imbalance (Occupancy 18%).
// Now: 256 thr / 16 rows / grid 1024 = 4 blocks/CU (16 waves/CU at ~110
// VGPR), blocks desynchronize -> chip-wide mixed read+write traffic.
//   Phase A (r8 mechanics, validated): wave = 512-k split; 16x
//     mfma_f32_16x16x32_bf16, both frags direct b128 global loads.
//     C/D: col=lane&15 (=r), row=(lane>>4)*4+reg.
//   B-slab (64 VGPR) loaded between the barriers -> L2 latency hides under
//     the 4-split reduce. (256,2): the only bounds that never clamp-spilled.
//   Phase B: 2 col-half iterations; per row: tmpl LDS broadcast + 64 FMA +
//     1KB coalesced store per wave.
// ---------------------------------------------------------------------------
#define FMA4(tv, R) \
  a.x = fmaf(tv, B4[R].x, a.x); a.y = fmaf(tv, B4[R].y, a.y); \
  a.z = fmaf(tv, B4[R].z, a.z); a.w = fmaf(tv, B4[R].w, a.w);

__global__ __launch_bounds__(256, 2) void lora_fused(
    const float* __restrict__ X,            // [8][2048][2048]
    const __hip_bfloat16* __restrict__ Amt, // [8][16][2048] bf16
    const float* __restrict__ Bm,           // [8][16][2048] fp32 (pre-scaled)
    float* __restrict__ out)                // [8][2048][2048]
{
  __shared__ float part[4][16][17];                // 4.4 KB
  __shared__ __align__(16) float tmpl[16][RANK];   // 1 KB

  const int tid  = threadIdx.x;
  const int lane = tid & 63;
  const int wv   = tid >> 6;               // 0..3 = 512-k split
  const int b    = blockIdx.x >> 7;        // 8 batches x 128 row-tiles
  const int row0 = (blockIdx.x & 127) * 16;
  const int m    = lane & 15;              // row-in-tile / r
  const int g    = lane >> 4;              // k-subgroup 0..3

  // ---------------- phase A: MFMA over this wave's 512-k split --------------
  const float* Xp = X + ((size_t)(b * 2048 + row0 + m)) * 2048 + wv * 512 + g * 8;
  const __hip_bfloat16* Ap = Amt + ((size_t)(b * 16 + m)) * 2048 + wv * 512 + g * 8;

  f32x4 acc = {0.f, 0.f, 0.f, 0.f};
#pragma unroll 4
  for (int kg = 0; kg < 16; ++kg) {        // 16 x (K=32) = 512 k
    const float4 xlo = *reinterpret_cast<const float4*>(Xp + (size_t)kg * 32);
    const float4 xhi = *reinterpret_cast<const float4*>(Xp + (size_t)kg * 32 + 4);
    bf16x8 afrag;
    afrag[0] = f2bf(xlo.x); afrag[1] = f2bf(xlo.y);
    afrag[2] = f2bf(xlo.z); afrag[3] = f2bf(xlo.w);
    afrag[4] = f2bf(xhi.x); afrag[5] = f2bf(xhi.y);
    afrag[6] = f2bf(xhi.z); afrag[7] = f2bf(xhi.w);
    const bf16x8 bfrag = *reinterpret_cast<const bf16x8*>(Ap + (size_t)kg * 32);
    acc = __builtin_amdgcn_mfma_f32_16x16x32_bf16(afrag, bfrag, acc, 0, 0, 0);
  }

  // park partials: lane holds tmp[row = g*4+v][r = m] for split wv
#pragma unroll
  for (int v = 0; v < 4; ++v)
    part[wv][g * 4 + v][m] = acc[v];

  __syncthreads();

  // ---- B-slab for col-half 0 (L2-hot), latency hidden under the reduce ----
  const int oc = wv * 256 + lane * 4;      // this thread's 4 cols in a half
  const float* Bb = Bm + (size_t)b * (RANK * 2048);
  float4 B4[RANK];
#pragma unroll
  for (int r = 0; r < RANK; ++r)
    B4[r] = *reinterpret_cast<const float4*>(Bb + (size_t)r * 2048 + oc);

  // ---- reduce 4 k-splits -> tmpl[16][16] (256 threads = 256 elems) --------
  {
    const int row = tid >> 4;
    const int r   = tid & 15;
    tmpl[row][r] = part[0][row][r] + part[1][row][r]
                 + part[2][row][r] + part[3][row][r];
  }
  __syncthreads();

  // ---------------- phase B: 16 rows x 2048 cols (2 half-iterations) --------
  float* op = out + ((size_t)(b * 2048 + row0)) * 2048;

#pragma unroll
  for (int it = 0; it < 2; ++it) {
    if (it == 1) {
      // reload slab for col-half 1
#pragma unroll
      for (int r = 0; r < RANK; ++r)
        B4[r] = *reinterpret_cast<const float4*>(Bb + (size_t)r * 2048 + 1024 + oc);
    }
    const int o0 = it * 1024 + oc;
#pragma unroll 4
    for (int rr = 0; rr < 16; ++rr) {
      const float4 t0 = *reinterpret_cast<const float4*>(&tmpl[rr][0]);   // LDS
      const float4 t1 = *reinterpret_cast<const float4*>(&tmpl[rr][4]);   // bcast
      const float4 t2 = *reinterpret_cast<const float4*>(&tmpl[rr][8]);
      const float4 t3 = *reinterpret_cast<const float4*>(&tmpl[rr][12]);
      float4 a = make_float4(0.f, 0.f, 0.f, 0.f);
      FMA4(t0.x, 0)  FMA4(t0.y, 1)  FMA4(t0.z, 2)  FMA4(t0.w, 3)
      FMA4(t1.x, 4)  FMA4(t1.y, 5)  FMA4(t1.z, 6)  FMA4(t1.w, 7)
      FMA4(t2.x, 8)  FMA4(t2.y, 9)  FMA4(t2.z, 10) FMA4(t2.w, 11)
      FMA4(t3.x, 12) FMA4(t3.y, 13) FMA4(t3.z, 14) FMA4(t3.w, 15)
      *reinterpret_cast<float4*>(op + (size_t)rr * 2048 + o0) = a;
    }
  }
}

// ---------------------------------------------------------------------------
extern "C" void kernel_launch(void* const* d_in, const int* in_sizes, int n_in,
                              void* d_out, int out_size, void* d_ws, size_t ws_size,
                              hipStream_t stream) {
  const float* input = (const float*)d_in[0];   // [8][2048][2048]
  const float* w     = (const float*)d_in[1];   // [8][4][8]
  const float* la    = (const float*)d_in[2];   // [4][8][512][16]
  const float* lb    = (const float*)d_in[3];   // [4][8][16][512]
  float* outp = (float*)d_out;

  __hip_bfloat16* Amt = (__hip_bfloat16*)d_ws;                    // 512 KB
  float* Bm = (float*)((char*)d_ws + (size_t)8 * 16 * 2048 * 2);  // 1 MB

  skilled_lora_mix<<<512, 256, 0, stream>>>(w, la, lb, Amt, Bm);
  lora_fused<<<1024, 256, 0, stream>>>(input, Amt, Bm, outp);
}

// Round 16
// 65.942 us; speedup vs baseline: 1.3880x; 1.2228x over previous
//
#include <hip/hip_runtime.h>
#include <hip/hip_bf16.h>
#include <cstdint>
#include <cstddef>

#define RANK 16

typedef __attribute__((ext_vector_type(8))) short bf16x8;   // 8 bf16 (4 VGPRs)
typedef __attribute__((ext_vector_type(4))) float f32x4;    // MFMA C/D

static __device__ __forceinline__ short f2bf(float f) {
  __hip_bfloat16 h = __float2bfloat16(f);
  return *reinterpret_cast<short*>(&h);
}

// ---------------------------------------------------------------------------
// Kernel 1: mix LoRA factors with per-(batch,split) skill weights.
//   Amt[b][r][k] = bf16( sum_s w[b][q][s] * la[q][s][d][r] ), k = q*512 + d
//   Bm[b][r][o]  = 2 * sum_s w[b][q][s] * lb[q][s][r][dd],   o = q*512 + dd
// (unchanged from the 79.6us r12 build)
// ---------------------------------------------------------------------------
__global__ __launch_bounds__(256) void skilled_lora_mix(
    const float* __restrict__ w,       // [8][4][8]
    const float* __restrict__ la,      // [4][8][512][16]
    const float* __restrict__ lb,      // [4][8][16][512]
    __hip_bfloat16* __restrict__ Amt,  // [8][16][2048] bf16
    float* __restrict__ Bm)            // [8][16][2048] fp32, pre-scaled by 2
{
  const int j = blockIdx.x * 256 + threadIdx.x;
  if (j < 65536) {
    const int r0 = (j & 3) * 4;
    const int k  = (j >> 2) & 2047;
    const int b  = j >> 13;
    const int q  = k >> 9;
    const int d  = k & 511;
    const float* wb = w + (b * 4 + q) * 8;
    float4 acc = make_float4(0.f, 0.f, 0.f, 0.f);
#pragma unroll
    for (int s = 0; s < 8; ++s) {
      const float ws = wb[s];
      const float4 v = *reinterpret_cast<const float4*>(
          la + (size_t)(((q * 8 + s) * 512 + d) * 16 + r0));
      acc.x = fmaf(ws, v.x, acc.x);
      acc.y = fmaf(ws, v.y, acc.y);
      acc.z = fmaf(ws, v.z, acc.z);
      acc.w = fmaf(ws, v.w, acc.w);
    }
    Amt[((size_t)(b * 16 + r0 + 0)) * 2048 + k] = __float2bfloat16(acc.x);
    Amt[((size_t)(b * 16 + r0 + 1)) * 2048 + k] = __float2bfloat16(acc.y);
    Amt[((size_t)(b * 16 + r0 + 2)) * 2048 + k] = __float2bfloat16(acc.z);
    Amt[((size_t)(b * 16 + r0 + 3)) * 2048 + k] = __float2bfloat16(acc.w);
  } else {
    const int jj = j - 65536;
    const int o  = (jj & 511) * 4;
    const int r  = (jj >> 9) & 15;
    const int b  = jj >> 13;
    const int q  = o >> 9;
    const int dd = o & 511;
    const float* wb = w + (b * 4 + q) * 8;
    float4 acc = make_float4(0.f, 0.f, 0.f, 0.f);
#pragma unroll
    for (int s = 0; s < 8; ++s) {
      const float ws = wb[s];
      const float4 v = *reinterpret_cast<const float4*>(
          lb + (size_t)(((q * 8 + s) * 16 + r) * 512 + dd));
      acc.x = fmaf(ws, v.x, acc.x);
      acc.y = fmaf(ws, v.y, acc.y);
      acc.z = fmaf(ws, v.z, acc.z);
      acc.w = fmaf(ws, v.w, acc.w);
    }
    acc.x *= 2.f; acc.y *= 2.f; acc.z *= 2.f; acc.w *= 2.f;
    *reinterpret_cast<float4*>(Bm + (size_t)((b * 16 + r) * 2048 + o)) = acc;
  }
}

// ---------------------------------------------------------------------------
// Kernel 2 (phase A): unchanged from the 79.6us r12 build (best measured:
// staged wave-private LDS, coalesced b128 staging, (256,8), grid 2048 =
// 8b x 128 tiles x 2 k-splits). Phase A runs at ~2.9 TB/s read, which is
// ~92% of the empirically observed per-direction read ceiling (~3.15 TB/s,
// inferred from m13 copy = 6.29 total / 2 directions); leave it.
// ---------------------------------------------------------------------------
__global__ __launch_bounds__(256, 8) void lora_phase_a(
    const float* __restrict__ X,           // [8][2048][2048]
    const __hip_bfloat16* __restrict__ Amt,// [8][16][2048] bf16
    float* __restrict__ tmp_p)             // [2][8][2048][16] partials
{
  __shared__ float lds[4 * 16 * 68];       // 17.4 KB

  const int tid  = threadIdx.x;
  const int lane = tid & 63;
  const int wv   = tid >> 6;               // 0..3: 256-k sub-window
  const int b    = blockIdx.x >> 8;        // 8 batches
  const int tile = (blockIdx.x >> 1) & 127;
  const int ks   = blockIdx.x & 1;         // k-split 0..1
  const int row0 = tile * 16;
  const int k0   = ks * 1024 + wv * 256;
  const int m    = lane & 15;              // fragment row / r
  const int g    = lane >> 4;              // k-subgroup 0..3

  float* stage = lds + wv * (16 * 68);     // wave-private [16][68]

  const int ms = lane >> 2;                // staging row 0..15
  const int cs = (lane & 3) * 4;           // staging 16B chunk (floats)

  const float* Xb = X + ((size_t)(b * 2048 + row0)) * 2048 + k0;
  const __hip_bfloat16* Ap = Amt + ((size_t)(b * 16 + m)) * 2048 + k0 + g * 8;

  f32x4 acc = {0.f, 0.f, 0.f, 0.f};

  for (int c = 0; c < 4; ++c) {            // 4 chunks of 64 k
    const int kc = c * 64;
#pragma unroll
    for (int i = 0; i < 4; ++i) {
      const float4 v = *reinterpret_cast<const float4*>(
          Xb + (size_t)ms * 2048 + kc + i * 16 + cs);
      *reinterpret_cast<float4*>(&stage[ms * 68 + i * 16 + cs]) = v;
    }
    // wave-private LDS; compiler inserts the vmcnt/lgkmcnt; no barrier.
#pragma unroll
    for (int h = 0; h < 2; ++h) {
      const float4 xlo = *reinterpret_cast<const float4*>(
          &stage[m * 68 + h * 32 + g * 8]);
      const float4 xhi = *reinterpret_cast<const float4*>(
          &stage[m * 68 + h * 32 + g * 8 + 4]);
      bf16x8 afrag;
      afrag[0] = f2bf(xlo.x); afrag[1] = f2bf(xlo.y);
      afrag[2] = f2bf(xlo.z); afrag[3] = f2bf(xlo.w);
      afrag[4] = f2bf(xhi.x); afrag[5] = f2bf(xhi.y);
      afrag[6] = f2bf(xhi.z); afrag[7] = f2bf(xhi.w);
      const bf16x8 bfrag = *reinterpret_cast<const bf16x8*>(
          Ap + (size_t)(c * 2 + h) * 32);
      acc = __builtin_amdgcn_mfma_f32_16x16x32_bf16(afrag, bfrag, acc, 0, 0, 0);
    }
  }

  __syncthreads();                         // all waves done with stage
  float* part = lds;
#pragma unroll
  for (int v = 0; v < 4; ++v)
    part[(wv * 16 + g * 4 + v) * 17 + m] = acc[v];
  __syncthreads();

  const int row = tid >> 4;                // 0..15
  const int r   = tid & 15;
  const float s = part[(0 * 16 + row) * 17 + r] + part[(1 * 16 + row) * 17 + r]
                + part[(2 * 16 + row) * 17 + r] + part[(3 * 16 + row) * 17 + r];
  tmp_p[((size_t)((ks * 8 + b) * 2048 + row0 + row)) * RANK + r] = s;
}

// ---------------------------------------------------------------------------
// Kernel 3 (phase B v2): out[b][row][o] = sum_r (tmp0+tmp1)[row][r] * Bm[r][o]
//
// ROUND-16: phase B was store-occupancy-limited: 64-VGPR fp32 B-slab ->
// ~100 VGPR -> 2 blocks/CU = 8 waves/CU -> 4.6 TB/s writes (fill kernel at
// 32 waves/CU does 7). Thread now owns 2 cols: B-slab = 16x float2 = 32
// VGPR, live set ~60-70 -> ~7 blocks/CU = 28 waves/CU. Stores dwordx2
// (512B/wave-instr, coalesced). Grid 2048 = 8b x 64 rowtiles(32) x 4
// colgroups(512); 32 rows/thread; tmp rows block-uniform scalar loads.
// ---------------------------------------------------------------------------
__global__ __launch_bounds__(256, 2) void lora_phase_b(
    const float* __restrict__ tmp_p, // [2][8][2048][16] partials
    const float* __restrict__ Bm,    // [8][16][2048] (pre-scaled by 2)
    float* __restrict__ out)         // [8][2048][2048]
{
  const int tid  = threadIdx.x;
  const int b    = blockIdx.x >> 8;          // 8 batches
  const int rt   = (blockIdx.x >> 2) & 63;   // row tile (32 rows)
  const int og   = blockIdx.x & 3;           // column group (512 cols)
  const int row0 = rt * 32;
  const int o0   = og * 512 + tid * 2;

  const float* Bb = Bm + (size_t)b * (RANK * 2048) + o0;
  float2 B2[RANK];
#pragma unroll
  for (int r = 0; r < RANK; ++r)
    B2[r] = *reinterpret_cast<const float2*>(Bb + (size_t)r * 2048);

  const float* tp0 = tmp_p + ((size_t)(b * 2048 + row0)) * RANK;
  const float* tp1 = tmp_p + ((size_t)((8 + b) * 2048 + row0)) * RANK;
  float* op = out + ((size_t)(b * 2048 + row0)) * 2048 + o0;

#pragma unroll 4
  for (int rr = 0; rr < 32; ++rr) {
    const float4 u0 = *reinterpret_cast<const float4*>(tp0 + rr * RANK);
    const float4 u1 = *reinterpret_cast<const float4*>(tp0 + rr * RANK + 4);
    const float4 u2 = *reinterpret_cast<const float4*>(tp0 + rr * RANK + 8);
    const float4 u3 = *reinterpret_cast<const float4*>(tp0 + rr * RANK + 12);
    const float4 v0 = *reinterpret_cast<const float4*>(tp1 + rr * RANK);
    const float4 v1 = *reinterpret_cast<const float4*>(tp1 + rr * RANK + 4);
    const float4 v2 = *reinterpret_cast<const float4*>(tp1 + rr * RANK + 8);
    const float4 v3 = *reinterpret_cast<const float4*>(tp1 + rr * RANK + 12);
    const float t0x = u0.x + v0.x, t0y = u0.y + v0.y, t0z = u0.z + v0.z, t0w = u0.w + v0.w;
    const float t1x = u1.x + v1.x, t1y = u1.y + v1.y, t1z = u1.z + v1.z, t1w = u1.w + v1.w;
    const float t2x = u2.x + v2.x, t2y = u2.y + v2.y, t2z = u2.z + v2.z, t2w = u2.w + v2.w;
    const float t3x = u3.x + v3.x, t3y = u3.y + v3.y, t3z = u3.z + v3.z, t3w = u3.w + v3.w;
    float2 a = make_float2(0.f, 0.f);
    a.x = fmaf(t0x, B2[0].x,  a.x);  a.y = fmaf(t0x, B2[0].y,  a.y);
    a.x = fmaf(t0y, B2[1].x,  a.x);  a.y = fmaf(t0y, B2[1].y,  a.y);
    a.x = fmaf(t0z, B2[2].x,  a.x);  a.y = fmaf(t0z, B2[2].y,  a.y);
    a.x = fmaf(t0w, B2[3].x,  a.x);  a.y = fmaf(t0w, B2[3].y,  a.y);
    a.x = fmaf(t1x, B2[4].x,  a.x);  a.y = fmaf(t1x, B2[4].y,  a.y);
    a.x = fmaf(t1y, B2[5].x,  a.x);  a.y = fmaf(t1y, B2[5].y,  a.y);
    a.x = fmaf(t1z, B2[6].x,  a.x);  a.y = fmaf(t1z, B2[6].y,  a.y);
    a.x = fmaf(t1w, B2[7].x,  a.x);  a.y = fmaf(t1w, B2[7].y,  a.y);
    a.x = fmaf(t2x, B2[8].x,  a.x);  a.y = fmaf(t2x, B2[8].y,  a.y);
    a.x = fmaf(t2y, B2[9].x,  a.x);  a.y = fmaf(t2y, B2[9].y,  a.y);
    a.x = fmaf(t2z, B2[10].x, a.x);  a.y = fmaf(t2z, B2[10].y, a.y);
    a.x = fmaf(t2w, B2[11].x, a.x);  a.y = fmaf(t2w, B2[11].y, a.y);
    a.x = fmaf(t3x, B2[12].x, a.x);  a.y = fmaf(t3x, B2[12].y, a.y);
    a.x = fmaf(t3y, B2[13].x, a.x);  a.y = fmaf(t3y, B2[13].y, a.y);
    a.x = fmaf(t3z, B2[14].x, a.x);  a.y = fmaf(t3z, B2[14].y, a.y);
    a.x = fmaf(t3w, B2[15].x, a.x);  a.y = fmaf(t3w, B2[15].y, a.y);
    *reinterpret_cast<float2*>(op + (size_t)rr * 2048) = a;
  }
}

// ---------------------------------------------------------------------------
extern "C" void kernel_launch(void* const* d_in, const int* in_sizes, int n_in,
                              void* d_out, int out_size, void* d_ws, size_t ws_size,
                              hipStream_t stream) {
  const float* input = (const float*)d_in[0];   // [8][2048][2048]
  const float* w     = (const float*)d_in[1];   // [8][4][8]
  const float* la    = (const float*)d_in[2];   // [4][8][512][16]
  const float* lb    = (const float*)d_in[3];   // [4][8][16][512]
  float* outp = (float*)d_out;

  __hip_bfloat16* Amt = (__hip_bfloat16*)d_ws;                      // 512 KB
  float* Bm    = (float*)((char*)d_ws + (size_t)8 * 16 * 2048 * 2); // 1 MB
  float* tmp_p = Bm + 8 * RANK * 2048;                              // 2 MB

  skilled_lora_mix<<<512, 256, 0, stream>>>(w, la, lb, Amt, Bm);
  lora_phase_a<<<2048, 256, 0, stream>>>(input, Amt, tmp_p);
  lora_phase_b<<<2048, 256, 0, stream>>>(tmp_p, Bm, outp);
}